// Round 3
// baseline (596.119 us; speedup 1.0000x reference)
//
#include <hip/hip_runtime.h>

#define NN  1024
#define EMB 128
#define HID 128

typedef __attribute__((ext_vector_type(4))) float float4v;
typedef __attribute__((ext_vector_type(8))) float float8v;
typedef __attribute__((ext_vector_type(8))) short short8;
typedef __attribute__((ext_vector_type(4))) __bf16 bf16x4;
typedef __attribute__((ext_vector_type(8))) __bf16 bf16x8;

__device__ __forceinline__ short8 to_bf16x8(float4v a, float4v b) {
  float8v f = {a[0], a[1], a[2], a[3], b[0], b[1], b[2], b[3]};
  bf16x8 r = __builtin_convertvector(f, bf16x8);   // v_cvt_pk_bf16_f32 x4 on gfx950
  return __builtin_bit_cast(short8, r);
}

__device__ __forceinline__ void store_bf16x4(short* p, float4v v) {
  bf16x4 r = __builtin_convertvector(v, bf16x4);
  *(bf16x4*)p = r;
}

// tanh-form GELU, vectorized; ONE v_rcp per 4 elements via shared reciprocal:
// rv_i = 1/d_i recovered from rcp(d0*d1*d2*d3). d_i = 1+2^y >= 1, and
// |x|<4.5 => y<20 => product < 2^80 < FLT_MAX: no overflow.
__device__ __forceinline__ float4v gelu4(float4v x) {
  float4v x2 = x * x;
  float4v t = x2 * 0.1029432f + 2.3022086f;   // 2*sqrt(2/pi)*log2e*(1+0.044715x^2)
  float4v y = x * t;
  float4v e;
  e[0] = __builtin_amdgcn_exp2f(y[0]);
  e[1] = __builtin_amdgcn_exp2f(y[1]);
  e[2] = __builtin_amdgcn_exp2f(y[2]);
  e[3] = __builtin_amdgcn_exp2f(y[3]);
  float4v d = e + 1.0f;
  float p01 = d[0] * d[1];
  float p23 = d[2] * d[3];
  float rall = __builtin_amdgcn_rcpf(p01 * p23);
  float r01 = p23 * rall;                     // 1/(d0*d1)
  float r23 = p01 * rall;                     // 1/(d2*d3)
  float4v rv;
  rv[0] = d[1] * r01;
  rv[1] = d[0] * r01;
  rv[2] = d[3] * r23;
  rv[3] = d[2] * r23;
  return x - x * rv;                          // x*sigmoid(2*inner)
}

__device__ __forceinline__ float4v mfma16(short8 a, short8 b, float4v c) {
  return __builtin_amdgcn_mfma_f32_16x16x32_bf16(a, b, c, 0, 0, 0);
}

// ---------------------------------------------------------------------------
// prep: blocks 0..63   -> Abuf[j,h] = z1[j,:]·W1a[h,:] + b1[h]
//       blocks 64..127 -> Bbuf[i,h] = z2[i,:]·W1b[h,:]
//       blocks 128..135-> W2f: bf16(W2) pre-swizzled into B-frag order
// All global loads coalesced; z and W1 staged in LDS in MFMA fragment order.
// ---------------------------------------------------------------------------
__global__ __launch_bounds__(256)
void prep_kernel(const float* __restrict__ z1, const float* __restrict__ z2,
                 const float* __restrict__ W1, const float* __restrict__ b1,
                 const float* __restrict__ W2,
                 float* __restrict__ Abuf, float* __restrict__ Bbuf,
                 unsigned short* __restrict__ W2f) {
  int blk = blockIdx.x, tid = threadIdx.x;
  if (blk < 128) {
    int which = blk >> 6;            // 0: A (z1,W1a,+b1)  1: B (z2,W1b)
    int j0 = (blk & 63) << 4;
    const float* z = which ? z2 : z1;
    __shared__ __align__(16) short zf[4 * 64 * 8];     // 4 KB  a-frags (per kt)
    __shared__ __align__(16) short w1f[HID * HID];     // 32 KB b-frags

    // stage z-tile (16x128 f32, coalesced) -> bf16 a-frag order
    {
      int row = tid >> 4;            // 0..15 (j within tile)
      int col = (tid & 15) * 8;      // 0..120 (k)
      const float* zp = z + (j0 + row) * EMB + col;
      float4v v0 = *(const float4v*)zp;
      float4v v1 = *(const float4v*)(zp + 4);
      int kt = col >> 5;
      int lane = ((col >> 3) & 3) * 16 + row;
      *(short8*)(zf + (kt * 64 + lane) * 8) = to_bf16x8(v0, v1);
    }
    // stage W1 chunk (128 rows x 128 cols, coalesced: wave covers 2 full rows)
    {
      const float* wbase = W1 + which * EMB;
#pragma unroll
      for (int p = 0; p < 16; ++p) {
        int u = p * 256 + tid;       // float4-unit id 0..4095
        int g = u >> 5;              // 0..127
        int c = (u & 31) * 4;        // 0..124
        float4v v = *(const float4v*)(wbase + g * (2 * EMB) + c);
        int kt = c >> 5;
        int nt = g >> 4;
        int lane = ((c >> 3) & 3) * 16 + (g & 15);
        store_bf16x4(w1f + ((kt * 8 + nt) * 64 + lane) * 8 + (c & 7), v);
      }
    }
    __syncthreads();

    int w = tid >> 6, l = tid & 63, r = l & 15, q = l >> 4;
    float4v acc0 = {}, acc1 = {};
#pragma unroll
    for (int kt = 0; kt < 4; ++kt) {
      short8 az  = *(const short8*)(zf + (kt * 64 + l) * 8);
      short8 bf0 = *(const short8*)(w1f + ((kt * 8 + w * 2) * 64 + l) * 8);
      short8 bf1 = *(const short8*)(w1f + ((kt * 8 + w * 2 + 1) * 64 + l) * 8);
      acc0 = mfma16(az, bf0, acc0);
      acc1 = mfma16(az, bf1, acc1);
    }
    float ba0 = which ? 0.0f : b1[w * 32 + r];
    float ba1 = which ? 0.0f : b1[w * 32 + 16 + r];
    float* dstp = which ? Bbuf : Abuf;
#pragma unroll
    for (int reg = 0; reg < 4; ++reg) {
      int row = j0 + q * 4 + reg;
      dstp[row * HID + w * 32 + r]      = acc0[reg] + ba0;
      dstp[row * HID + w * 32 + 16 + r] = acc1[reg] + ba1;
    }
  } else {
    int idx = (blk - 128) * 2048 + tid * 8;    // 8 blocks * 2048 = 16384 elems
    int lane = (idx >> 3) & 63;
    int nt = (idx >> 9) & 7;
    int kt = idx >> 12;
    int g = nt * 16 + (lane & 15);
    int hb = kt * 32 + (lane >> 4) * 8;
#pragma unroll
    for (int j = 0; j < 8; ++j) {
      unsigned u = __float_as_uint(W2[g * HID + hb + j]);
      W2f[idx + j] = (unsigned short)((u + 0x7FFFu + ((u >> 16) & 1u)) >> 16);  // RNE
    }
  }
}

// ---------------------------------------------------------------------------
// main (persistent): grid=1024, each block fills W2 LDS once then processes 8
// tiles (8i x 16j) with NO barriers. bj fixed per block -> A-tile L1-resident.
// Wave owns 2 i-rows -> acc[2][8] (64 AGPRs), 4 waves/SIMD.
// ---------------------------------------------------------------------------
__global__ __launch_bounds__(256, 4)
void fused_mlp_kernel(const float* __restrict__ Abuf, const float* __restrict__ Bbuf,
                      const float* __restrict__ W2f4,  // packed bf16 frags
                      const float* __restrict__ b2, const float* __restrict__ W3,
                      const float* __restrict__ b3, float* __restrict__ out) {
  __shared__ __align__(16) short s_w2[HID * HID];  // 32 KB, fragment order

  int tid = threadIdx.x;
  {
    const float4v* src = (const float4v*)W2f4;
    float4v* dst = (float4v*)s_w2;
#pragma unroll
    for (int t = 0; t < 8; ++t)
      dst[tid + t * 256] = src[tid + t * 256];
  }

  int w = tid >> 6, l = tid & 63, r = l & 15, q = l >> 4;

  float b2v[8], w3v[8];
#pragma unroll
  for (int nt = 0; nt < 8; ++nt) {
    b2v[nt] = b2[nt * 16 + r];
    w3v[nt] = W3[nt * 16 + r];
  }
  float bias3 = b3[0];

  int bj = (blockIdx.x & 63) << 4;            // fixed per block
  const float* Arow = Abuf + (bj + r) * HID;  // A'[j=bj+r][h]

  __syncthreads();

  for (int t = blockIdx.x; t < 64 * 128; t += 1024) {
    int bi = (t >> 6) << 3;
    const float* B0 = Bbuf + (bi + w * 2) * HID;
    const float* B1 = B0 + HID;

    float4v acc[2][8] = {};

#pragma unroll
    for (int kt = 0; kt < 4; ++kt) {
      int h0 = kt * 32 + q * 8;
      float4v a0 = *(const float4v*)(Arow + h0);
      float4v a1 = *(const float4v*)(Arow + h0 + 4);

      float4v g00 = gelu4(a0 + *(const float4v*)(B0 + h0));
      float4v g01 = gelu4(a1 + *(const float4v*)(B0 + h0 + 4));
      float4v g10 = gelu4(a0 + *(const float4v*)(B1 + h0));
      float4v g11 = gelu4(a1 + *(const float4v*)(B1 + h0 + 4));
      short8 af0 = to_bf16x8(g00, g01);
      short8 af1 = to_bf16x8(g10, g11);

      const short8* wrow = (const short8*)s_w2 + kt * 8 * 64 + l;
#pragma unroll
      for (int nt = 0; nt < 8; ++nt) {
        short8 bfr = wrow[nt * 64];    // stride-16B, conflict-free
        acc[0][nt] = mfma16(af0, bfr, acc[0][nt]);
        acc[1][nt] = mfma16(af1, bfr, acc[1][nt]);
      }
    }

    // epilogue: h2 = gelu(acc + b2[g]); out = sum_g h2*W3[g] + b3
#pragma unroll
    for (int mt = 0; mt < 2; ++mt) {
      float4v s = {0.f, 0.f, 0.f, 0.f};
#pragma unroll
      for (int nt = 0; nt < 8; ++nt) {
        float4v xx = acc[mt][nt] + b2v[nt];
        s = s + gelu4(xx) * w3v[nt];
      }
#pragma unroll
      for (int mask = 1; mask < 16; mask <<= 1) {
#pragma unroll
        for (int reg = 0; reg < 4; ++reg)
          s[reg] += __shfl_xor(s[reg], mask, 64);
      }
      if (r < 4) {
        int irow = bi + w * 2 + mt;
        int jcol = bj + q * 4 + r;
        out[irow * NN + jcol] = s[r] + bias3;
      }
    }
  }
}

extern "C" void kernel_launch(void* const* d_in, const int* in_sizes, int n_in,
                              void* d_out, int out_size, void* d_ws, size_t ws_size,
                              hipStream_t stream) {
  const float* z1 = (const float*)d_in[0];
  const float* z2 = (const float*)d_in[1];
  const float* W1 = (const float*)d_in[2];
  const float* b1 = (const float*)d_in[3];
  const float* W2 = (const float*)d_in[4];
  const float* b2 = (const float*)d_in[5];
  const float* W3 = (const float*)d_in[6];
  const float* b3 = (const float*)d_in[7];
  float* out = (float*)d_out;

  float* Abuf = (float*)d_ws;                                // 512 KB
  float* Bbuf = Abuf + NN * HID;                             // 512 KB
  unsigned short* W2f = (unsigned short*)(Bbuf + NN * HID);  // 32 KB

  prep_kernel<<<136, 256, 0, stream>>>(z1, z2, W1, b1, W2, Abuf, Bbuf, W2f);
  fused_mlp_kernel<<<1024, 256, 0, stream>>>(
      Abuf, Bbuf, (const float*)W2f, b2, W3, b3, out);
}

// Round 4
// 168.277 us; speedup vs baseline: 3.5425x; 3.5425x over previous
//
#include <hip/hip_runtime.h>

#define NN  1024
#define EMB 128
#define HID 128

typedef __attribute__((ext_vector_type(4))) float float4v;
typedef __attribute__((ext_vector_type(8))) float float8v;
typedef __attribute__((ext_vector_type(8))) short short8;
typedef __attribute__((ext_vector_type(4))) __bf16 bf16x4;
typedef __attribute__((ext_vector_type(8))) __bf16 bf16x8;

__device__ __forceinline__ short8 to_bf16x8(float4v a, float4v b) {
  float8v f = {a[0], a[1], a[2], a[3], b[0], b[1], b[2], b[3]};
  bf16x8 r = __builtin_convertvector(f, bf16x8);   // v_cvt_pk_bf16_f32 x4
  return __builtin_bit_cast(short8, r);
}

__device__ __forceinline__ void store_bf16x4(short* p, float4v v) {
  bf16x4 r = __builtin_convertvector(v, bf16x4);
  *(bf16x4*)p = r;
}

// tanh-form GELU, vectorized; ONE v_rcp per 4 elements via shared reciprocal.
// d_i = 1+2^y >= 1, |x|<4.5 => product < 2^80: no overflow.
__device__ __forceinline__ float4v gelu4(float4v x) {
  float4v x2 = x * x;
  float4v t = x2 * 0.1029432f + 2.3022086f;   // 2*sqrt(2/pi)*log2e*(1+0.044715x^2)
  float4v y = x * t;
  float4v e;
  e[0] = __builtin_amdgcn_exp2f(y[0]);
  e[1] = __builtin_amdgcn_exp2f(y[1]);
  e[2] = __builtin_amdgcn_exp2f(y[2]);
  e[3] = __builtin_amdgcn_exp2f(y[3]);
  float4v d = e + 1.0f;
  float p01 = d[0] * d[1];
  float p23 = d[2] * d[3];
  float rall = __builtin_amdgcn_rcpf(p01 * p23);
  float r01 = p23 * rall;                     // 1/(d0*d1)
  float r23 = p01 * rall;                     // 1/(d2*d3)
  float4v rv;
  rv[0] = d[1] * r01;
  rv[1] = d[0] * r01;
  rv[2] = d[3] * r23;
  rv[3] = d[2] * r23;
  return x - x * rv;                          // x*sigmoid(2*inner)
}

__device__ __forceinline__ float4v mfma16(short8 a, short8 b, float4v c) {
  return __builtin_amdgcn_mfma_f32_16x16x32_bf16(a, b, c, 0, 0, 0);
}

// ---------------------------------------------------------------------------
// prep: blocks 0..63   -> Abuf[j,h] = z1[j,:]·W1a[h,:] + b1[h]
//       blocks 64..127 -> Bbuf[i,h] = z2[i,:]·W1b[h,:]
//       blocks 128..135-> W2f: bf16(W2) pre-swizzled into B-frag order
// All global loads coalesced; z and W1 staged in LDS in MFMA fragment order.
// (unchanged from round 3 — verified bit-identical output)
// ---------------------------------------------------------------------------
__global__ __launch_bounds__(256)
void prep_kernel(const float* __restrict__ z1, const float* __restrict__ z2,
                 const float* __restrict__ W1, const float* __restrict__ b1,
                 const float* __restrict__ W2,
                 float* __restrict__ Abuf, float* __restrict__ Bbuf,
                 unsigned short* __restrict__ W2f) {
  int blk = blockIdx.x, tid = threadIdx.x;
  if (blk < 128) {
    int which = blk >> 6;            // 0: A (z1,W1a,+b1)  1: B (z2,W1b)
    int j0 = (blk & 63) << 4;
    const float* z = which ? z2 : z1;
    __shared__ __align__(16) short zf[4 * 64 * 8];     // 4 KB  a-frags
    __shared__ __align__(16) short w1f[HID * HID];     // 32 KB b-frags

    {
      int row = tid >> 4;
      int col = (tid & 15) * 8;
      const float* zp = z + (j0 + row) * EMB + col;
      float4v v0 = *(const float4v*)zp;
      float4v v1 = *(const float4v*)(zp + 4);
      int kt = col >> 5;
      int lane = ((col >> 3) & 3) * 16 + row;
      *(short8*)(zf + (kt * 64 + lane) * 8) = to_bf16x8(v0, v1);
    }
    {
      const float* wbase = W1 + which * EMB;
#pragma unroll
      for (int p = 0; p < 16; ++p) {
        int u = p * 256 + tid;
        int g = u >> 5;
        int c = (u & 31) * 4;
        float4v v = *(const float4v*)(wbase + g * (2 * EMB) + c);
        int kt = c >> 5;
        int nt = g >> 4;
        int lane = ((c >> 3) & 3) * 16 + (g & 15);
        store_bf16x4(w1f + ((kt * 8 + nt) * 64 + lane) * 8 + (c & 7), v);
      }
    }
    __syncthreads();

    int w = tid >> 6, l = tid & 63, r = l & 15, q = l >> 4;
    float4v acc0 = {}, acc1 = {};
#pragma unroll
    for (int kt = 0; kt < 4; ++kt) {
      short8 az  = *(const short8*)(zf + (kt * 64 + l) * 8);
      short8 bf0 = *(const short8*)(w1f + ((kt * 8 + w * 2) * 64 + l) * 8);
      short8 bf1 = *(const short8*)(w1f + ((kt * 8 + w * 2 + 1) * 64 + l) * 8);
      acc0 = mfma16(az, bf0, acc0);
      acc1 = mfma16(az, bf1, acc1);
    }
    float ba0 = which ? 0.0f : b1[w * 32 + r];
    float ba1 = which ? 0.0f : b1[w * 32 + 16 + r];
    float* dstp = which ? Bbuf : Abuf;
#pragma unroll
    for (int reg = 0; reg < 4; ++reg) {
      int row = j0 + q * 4 + reg;
      dstp[row * HID + w * 32 + r]      = acc0[reg] + ba0;
      dstp[row * HID + w * 32 + 16 + r] = acc1[reg] + ba1;
    }
  } else {
    int idx = (blk - 128) * 2048 + tid * 8;
    int lane = (idx >> 3) & 63;
    int nt = (idx >> 9) & 7;
    int kt = idx >> 12;
    int g = nt * 16 + (lane & 15);
    int hb = kt * 32 + (lane >> 4) * 8;
#pragma unroll
    for (int j = 0; j < 8; ++j) {
      unsigned u = __float_as_uint(W2[g * HID + hb + j]);
      W2f[idx + j] = (unsigned short)((u + 0x7FFFu + ((u >> 16) & 1u)) >> 16);  // RNE
    }
  }
}

// ---------------------------------------------------------------------------
// main: one block = 8i x 16j tile, 512 threads (8 waves), wave owns 1 i-row.
// acc[8] = 32 regs; b2 folded into MFMA C-init; w3/b3 loaded in epilogue.
// __launch_bounds__(512,6): reg cap 85, 3 blocks/CU (96 KB LDS), 6 waves/SIMD.
// ---------------------------------------------------------------------------
__global__ __launch_bounds__(512, 6)
void fused_mlp_kernel(const float* __restrict__ Abuf, const float* __restrict__ Bbuf,
                      const float* __restrict__ W2f4,  // packed bf16 frags
                      const float* __restrict__ b2, const float* __restrict__ W3,
                      const float* __restrict__ b3, float* __restrict__ out) {
  __shared__ __align__(16) short s_w2[HID * HID];  // 32 KB, fragment order

  int tid = threadIdx.x;
  {
    const float4v* src = (const float4v*)W2f4;
    float4v* dst = (float4v*)s_w2;
#pragma unroll
    for (int t = 0; t < 4; ++t)
      dst[tid + t * 512] = src[tid + t * 512];
  }

  int w = tid >> 6, l = tid & 63, r = l & 15, q = l >> 4;
  int bi = (blockIdx.x >> 6) << 3;
  int bj = (blockIdx.x & 63) << 4;

  const float* Arow = Abuf + (bj + r) * HID;   // A'[j=bj+r][h]
  const float* Brow = Bbuf + (bi + w) * HID;   // B[i=bi+w][h]

  // b2 folded into accumulator init: C[m][g=nt*16+r] starts at b2[g]
  float4v acc[8];
#pragma unroll
  for (int nt = 0; nt < 8; ++nt) {
    float bv = b2[nt * 16 + r];
    acc[nt] = (float4v){bv, bv, bv, bv};
  }

  __syncthreads();

#pragma unroll
  for (int kt = 0; kt < 4; ++kt) {
    int h0 = kt * 32 + q * 8;
    float4v a0 = *(const float4v*)(Arow + h0);
    float4v a1 = *(const float4v*)(Arow + h0 + 4);
    float4v c0 = *(const float4v*)(Brow + h0);
    float4v c1 = *(const float4v*)(Brow + h0 + 4);
    short8 af = to_bf16x8(gelu4(a0 + c0), gelu4(a1 + c1));

    const short8* wrow = (const short8*)s_w2 + kt * 8 * 64 + l;
#pragma unroll
    for (int nt = 0; nt < 8; ++nt)
      acc[nt] = mfma16(af, wrow[nt * 64], acc[nt]);   // stride-16B, conflict-free
  }

  // epilogue: out = sum_g gelu(acc)[g] * W3[g] + b3
  float4v s = {0.f, 0.f, 0.f, 0.f};
#pragma unroll
  for (int nt = 0; nt < 8; ++nt) {
    float wv = W3[nt * 16 + r];
    s = s + gelu4(acc[nt]) * wv;
  }
#pragma unroll
  for (int mask = 1; mask < 16; mask <<= 1) {
#pragma unroll
    for (int reg = 0; reg < 4; ++reg)
      s[reg] += __shfl_xor(s[reg], mask, 64);
  }
  if (r < 4) {
    int irow = bi + w;
    int jcol = bj + q * 4 + r;
    out[irow * NN + jcol] = s[r] + b3[0];
  }
}

extern "C" void kernel_launch(void* const* d_in, const int* in_sizes, int n_in,
                              void* d_out, int out_size, void* d_ws, size_t ws_size,
                              hipStream_t stream) {
  const float* z1 = (const float*)d_in[0];
  const float* z2 = (const float*)d_in[1];
  const float* W1 = (const float*)d_in[2];
  const float* b1 = (const float*)d_in[3];
  const float* W2 = (const float*)d_in[4];
  const float* b2 = (const float*)d_in[5];
  const float* W3 = (const float*)d_in[6];
  const float* b3 = (const float*)d_in[7];
  float* out = (float*)d_out;

  float* Abuf = (float*)d_ws;                                // 512 KB
  float* Bbuf = Abuf + NN * HID;                             // 512 KB
  unsigned short* W2f = (unsigned short*)(Bbuf + NN * HID);  // 32 KB

  prep_kernel<<<136, 256, 0, stream>>>(z1, z2, W1, b1, W2, Abuf, Bbuf, W2f);
  fused_mlp_kernel<<<(NN / 8) * (NN / 16), 512, 0, stream>>>(
      Abuf, Bbuf, (const float*)W2f, b2, W3, b3, out);
}

// Round 5
// 158.126 us; speedup vs baseline: 3.7699x; 1.0642x over previous
//
#include <hip/hip_runtime.h>

#define NN  1024
#define EMB 128
#define HID 128

typedef __attribute__((ext_vector_type(4))) float float4v;
typedef __attribute__((ext_vector_type(8))) float float8v;
typedef __attribute__((ext_vector_type(8))) short short8;
typedef __attribute__((ext_vector_type(4))) __bf16 bf16x4;
typedef __attribute__((ext_vector_type(8))) __bf16 bf16x8;

__device__ __forceinline__ short8 to_bf16x8(float4v a, float4v b) {
  float8v f = {a[0], a[1], a[2], a[3], b[0], b[1], b[2], b[3]};
  bf16x8 r = __builtin_convertvector(f, bf16x8);   // v_cvt_pk_bf16_f32 x4
  return __builtin_bit_cast(short8, r);
}

__device__ __forceinline__ void store_bf16x4(short* p, float4v v) {
  bf16x4 r = __builtin_convertvector(v, bf16x4);
  *(bf16x4*)p = r;
}

// tanh-form GELU, vectorized; ONE v_rcp per 4 elements via shared reciprocal.
// d_i = 1+2^y >= 1, |x|<4.5 => product < 2^80: no overflow.
__device__ __forceinline__ float4v gelu4(float4v x) {
  float4v x2 = x * x;
  float4v t = x2 * 0.1029432f + 2.3022086f;   // 2*sqrt(2/pi)*log2e*(1+0.044715x^2)
  float4v y = x * t;
  float4v e;
  e[0] = __builtin_amdgcn_exp2f(y[0]);
  e[1] = __builtin_amdgcn_exp2f(y[1]);
  e[2] = __builtin_amdgcn_exp2f(y[2]);
  e[3] = __builtin_amdgcn_exp2f(y[3]);
  float4v d = e + 1.0f;
  float p01 = d[0] * d[1];
  float p23 = d[2] * d[3];
  float rall = __builtin_amdgcn_rcpf(p01 * p23);
  float r01 = p23 * rall;                     // 1/(d0*d1)
  float r23 = p01 * rall;                     // 1/(d2*d3)
  float4v rv;
  rv[0] = d[1] * r01;
  rv[1] = d[0] * r01;
  rv[2] = d[3] * r23;
  rv[3] = d[2] * r23;
  return x - x * rv;                          // x*sigmoid(2*inner)
}

__device__ __forceinline__ float4v mfma16(short8 a, short8 b, float4v c) {
  return __builtin_amdgcn_mfma_f32_16x16x32_bf16(a, b, c, 0, 0, 0);
}

// ---------------------------------------------------------------------------
// prep: blocks 0..127  -> Abuf[j, hh*64..+63] = z1[j,:]·W1a[g,:] + b1 (16 j x 64 g)
//       blocks 128..255-> Bbuf[i, hh*64..+63] = z2[i,:]·W1b[g,:]
//       blocks 256..263-> W2f: bf16(W2) pre-swizzled into MFMA frag order
//                         (coalesced reads, scattered ushort writes)
// 264 blocks: all CUs busy; all global reads coalesced.
// ---------------------------------------------------------------------------
__global__ __launch_bounds__(256)
void prep_kernel(const float* __restrict__ z1, const float* __restrict__ z2,
                 const float* __restrict__ W1, const float* __restrict__ b1,
                 const float* __restrict__ W2,
                 float* __restrict__ Abuf, float* __restrict__ Bbuf,
                 unsigned short* __restrict__ W2f) {
  int blk = blockIdx.x, tid = threadIdx.x;
  if (blk < 256) {
    int which = blk >> 7;                 // 0: A (z1,W1a,+b1)  1: B (z2,W1b)
    int j0 = ((blk & 127) >> 1) << 4;     // 16-row tile
    int hh = blk & 1;                     // h-half (64 g)
    const float* z = which ? z2 : z1;
    __shared__ __align__(16) short zf[4 * 64 * 8];    // 4 KB  z a-frags
    __shared__ __align__(16) short w1f[16 * 64 * 8];  // 16 KB W1 b-frags

    // stage z-tile (16x128 f32, coalesced) -> bf16 a-frag order
#pragma unroll
    for (int p = 0; p < 2; ++p) {
      int u = p * 256 + tid;
      int row = u >> 5;                   // 0..15
      int c = (u & 31) * 4;               // 0..124
      float4v v = *(const float4v*)(z + (j0 + row) * EMB + c);
      int kt = c >> 5;
      int lane = ((c >> 3) & 3) * 16 + row;
      store_bf16x4(zf + (kt * 64 + lane) * 8 + (c & 7), v);
    }
    // stage W1 quarter: rows g in [hh*64, hh*64+64), cols which*128..+127
    {
      const float* wbase = W1 + (hh * 64) * (2 * EMB) + which * EMB;
#pragma unroll
      for (int p = 0; p < 8; ++p) {
        int u = p * 256 + tid;
        int grow = u >> 5;                // 0..63
        int c = (u & 31) * 4;
        float4v v = *(const float4v*)(wbase + grow * (2 * EMB) + c);
        int kt = c >> 5;
        int ntl = grow >> 4;              // 0..3
        int lane = ((c >> 3) & 3) * 16 + (grow & 15);
        store_bf16x4(w1f + ((kt * 4 + ntl) * 64 + lane) * 8 + (c & 7), v);
      }
    }
    __syncthreads();

    int w = tid >> 6, l = tid & 63, r = l & 15, q = l >> 4;
    float4v acc = {};
#pragma unroll
    for (int kt = 0; kt < 4; ++kt) {
      short8 az = *(const short8*)(zf + (kt * 64 + l) * 8);
      short8 bf = *(const short8*)(w1f + ((kt * 4 + w) * 64 + l) * 8);
      acc = mfma16(az, bf, acc);
    }
    int gg = hh * 64 + w * 16 + r;
    float ba = which ? 0.0f : b1[gg];
    float* dstp = which ? Bbuf : Abuf;
#pragma unroll
    for (int reg = 0; reg < 4; ++reg)
      dstp[(j0 + q * 4 + reg) * HID + gg] = acc[reg] + ba;
  } else {
    // W2f swizzle: coalesced dwordx4 reads, scattered bf16 writes
    int s0 = (blk - 256) * 2048 + tid * 8;
    float4v v0 = *(const float4v*)(W2 + s0);
    float4v v1 = *(const float4v*)(W2 + s0 + 4);
    float vals[8] = {v0[0], v0[1], v0[2], v0[3], v1[0], v1[1], v1[2], v1[3]};
#pragma unroll
    for (int j = 0; j < 8; ++j) {
      int s = s0 + j;
      int g = s >> 7;
      int h = s & 127;
      int kt = h >> 5;
      int nt = g >> 4;
      int lane = ((h >> 3) & 3) * 16 + (g & 15);
      int dst = ((kt * 8 + nt) * 64 + lane) * 8 + (h & 7);
      unsigned u = __float_as_uint(vals[j]);
      W2f[dst] = (unsigned short)((u + 0x7FFFu + ((u >> 16) & 1u)) >> 16);  // RNE
    }
  }
}

// ---------------------------------------------------------------------------
// main: one block = 8i x 16j tile, 256 threads (4 waves), wave owns 2 i-rows.
// SWAPPED operands: D[g][pair] = W2 · h1^T  (A-operand = W2 frags from LDS,
// B-operand = h1 generated on the fly; A/B frag index math is symmetric).
// C-layout: col = lane&15 = pair(j), row = q*4+reg = g-local -> the W3 dot
// over g is in-lane over {nt,reg} + 2 shuffles (xor16,xor32). b2 folds into
// acc init as one aligned float4 load per nt. acc[2][8]=64 regs, (256,4).
// ---------------------------------------------------------------------------
__global__ __launch_bounds__(256, 4)
void fused_mlp_kernel(const float* __restrict__ Abuf, const float* __restrict__ Bbuf,
                      const float* __restrict__ W2f4,  // packed bf16 frags
                      const float* __restrict__ b2, const float* __restrict__ W3,
                      const float* __restrict__ b3, float* __restrict__ out) {
  __shared__ __align__(16) short s_w2[HID * HID];  // 32 KB, fragment order

  int tid = threadIdx.x;
  {
    const float4v* src = (const float4v*)W2f4;
    float4v* dst = (float4v*)s_w2;
#pragma unroll
    for (int t = 0; t < 8; ++t)
      dst[tid + t * 256] = src[tid + t * 256];
  }

  int w = tid >> 6, l = tid & 63, r = l & 15, q = l >> 4;
  int bi = (blockIdx.x >> 6) << 3;
  int bj = (blockIdx.x & 63) << 4;

  const float* Arow = Abuf + (bj + r) * HID;     // A'[j = bj + (l&15)][h]
  const float* B0 = Bbuf + (bi + 2 * w) * HID;   // B[i0]
  const float* B1 = B0 + HID;                    // B[i1]

  // acc[p][nt][reg] starts at b2[g = nt*16 + q*4 + reg]
  float4v acc[2][8];
#pragma unroll
  for (int nt = 0; nt < 8; ++nt) {
    float4v bv = *(const float4v*)(b2 + nt * 16 + q * 4);
    acc[0][nt] = bv;
    acc[1][nt] = bv;
  }

  __syncthreads();

#pragma unroll
  for (int kt = 0; kt < 4; ++kt) {
    int h0 = kt * 32 + q * 8;
    float4v a0 = *(const float4v*)(Arow + h0);
    float4v a1 = *(const float4v*)(Arow + h0 + 4);

    short8 af0 = to_bf16x8(gelu4(a0 + *(const float4v*)(B0 + h0)),
                           gelu4(a1 + *(const float4v*)(B0 + h0 + 4)));
    short8 af1 = to_bf16x8(gelu4(a0 + *(const float4v*)(B1 + h0)),
                           gelu4(a1 + *(const float4v*)(B1 + h0 + 4)));

    const short8* wrow = (const short8*)s_w2 + kt * 8 * 64 + l;
#pragma unroll
    for (int nt = 0; nt < 8; ++nt) {
      short8 wf = wrow[nt * 64];    // stride-16B, conflict-free
      acc[0][nt] = mfma16(wf, af0, acc[0][nt]);   // A = W2, B = h1
      acc[1][nt] = mfma16(wf, af1, acc[1][nt]);
    }
  }

  // epilogue: out[i, bj+n] = sum_g gelu(acc)[g][n] * W3[g] + b3
  float bias3 = b3[0];
#pragma unroll
  for (int p = 0; p < 2; ++p) {
    float4v s = {0.f, 0.f, 0.f, 0.f};
#pragma unroll
    for (int nt = 0; nt < 8; ++nt) {
      float4v wv = *(const float4v*)(W3 + nt * 16 + q * 4);
      s = s + gelu4(acc[p][nt]) * wv;
    }
    float sc = s[0] + s[1] + s[2] + s[3];   // in-lane over this q's 32 g
    sc += __shfl_xor(sc, 16, 64);           // merge q-groups
    sc += __shfl_xor(sc, 32, 64);
    if (l < 16)
      out[(bi + 2 * w + p) * NN + bj + l] = sc + bias3;
  }
}

extern "C" void kernel_launch(void* const* d_in, const int* in_sizes, int n_in,
                              void* d_out, int out_size, void* d_ws, size_t ws_size,
                              hipStream_t stream) {
  const float* z1 = (const float*)d_in[0];
  const float* z2 = (const float*)d_in[1];
  const float* W1 = (const float*)d_in[2];
  const float* b1 = (const float*)d_in[3];
  const float* W2 = (const float*)d_in[4];
  const float* b2 = (const float*)d_in[5];
  const float* W3 = (const float*)d_in[6];
  const float* b3 = (const float*)d_in[7];
  float* out = (float*)d_out;

  float* Abuf = (float*)d_ws;                                // 512 KB
  float* Bbuf = Abuf + NN * HID;                             // 512 KB
  unsigned short* W2f = (unsigned short*)(Bbuf + NN * HID);  // 32 KB

  prep_kernel<<<264, 256, 0, stream>>>(z1, z2, W1, b1, W2, Abuf, Bbuf, W2f);
  fused_mlp_kernel<<<(NN / 8) * (NN / 16), 256, 0, stream>>>(
      Abuf, Bbuf, (const float*)W2f, b2, W3, b3, out);
}

// Round 6
// 157.320 us; speedup vs baseline: 3.7892x; 1.0051x over previous
//
#include <hip/hip_runtime.h>

#define NN  1024
#define EMB 128
#define HID 128

typedef __attribute__((ext_vector_type(4))) float float4v;
typedef __attribute__((ext_vector_type(8))) float float8v;
typedef __attribute__((ext_vector_type(8))) short short8;
typedef __attribute__((ext_vector_type(4))) __bf16 bf16x4;
typedef __attribute__((ext_vector_type(8))) __bf16 bf16x8;

__device__ __forceinline__ short8 to_bf16x8(float4v a, float4v b) {
  float8v f = {a[0], a[1], a[2], a[3], b[0], b[1], b[2], b[3]};
  bf16x8 r = __builtin_convertvector(f, bf16x8);   // v_cvt_pk_bf16_f32 x4
  return __builtin_bit_cast(short8, r);
}

__device__ __forceinline__ void store_bf16x4(short* p, float4v v) {
  bf16x4 r = __builtin_convertvector(v, bf16x4);
  *(bf16x4*)p = r;
}

// tanh-form GELU, vectorized; ONE v_rcp per 4 elements via shared reciprocal.
// d_i = 1+2^y >= 1, |x|<4.5 => product < 2^80: no overflow.
__device__ __forceinline__ float4v gelu4(float4v x) {
  float4v x2 = x * x;
  float4v t = x2 * 0.1029432f + 2.3022086f;   // 2*sqrt(2/pi)*log2e*(1+0.044715x^2)
  float4v y = x * t;
  float4v e;
  e[0] = __builtin_amdgcn_exp2f(y[0]);
  e[1] = __builtin_amdgcn_exp2f(y[1]);
  e[2] = __builtin_amdgcn_exp2f(y[2]);
  e[3] = __builtin_amdgcn_exp2f(y[3]);
  float4v d = e + 1.0f;
  float p01 = d[0] * d[1];
  float p23 = d[2] * d[3];
  float rall = __builtin_amdgcn_rcpf(p01 * p23);
  float r01 = p23 * rall;                     // 1/(d0*d1)
  float r23 = p01 * rall;                     // 1/(d2*d3)
  float4v rv;
  rv[0] = d[1] * r01;
  rv[1] = d[0] * r01;
  rv[2] = d[3] * r23;
  rv[3] = d[2] * r23;
  return x - x * rv;                          // x*sigmoid(2*inner)
}

__device__ __forceinline__ float4v mfma16(short8 a, short8 b, float4v c) {
  return __builtin_amdgcn_mfma_f32_16x16x32_bf16(a, b, c, 0, 0, 0);
}

// ---------------------------------------------------------------------------
// prep: blocks 0..127  -> Abuf[j, hh*64..+63] = z1[j,:]·W1a[g,:] + b1 (16 j x 64 g)
//       blocks 128..255-> Bbuf[i, hh*64..+63] = z2[i,:]·W1b[g,:]
//       blocks 256..263-> W2f: bf16(W2) pre-swizzled into MFMA frag order
// (unchanged from round 5)
// ---------------------------------------------------------------------------
__global__ __launch_bounds__(256)
void prep_kernel(const float* __restrict__ z1, const float* __restrict__ z2,
                 const float* __restrict__ W1, const float* __restrict__ b1,
                 const float* __restrict__ W2,
                 float* __restrict__ Abuf, float* __restrict__ Bbuf,
                 unsigned short* __restrict__ W2f) {
  int blk = blockIdx.x, tid = threadIdx.x;
  if (blk < 256) {
    int which = blk >> 7;                 // 0: A (z1,W1a,+b1)  1: B (z2,W1b)
    int j0 = ((blk & 127) >> 1) << 4;     // 16-row tile
    int hh = blk & 1;                     // h-half (64 g)
    const float* z = which ? z2 : z1;
    __shared__ __align__(16) short zf[4 * 64 * 8];    // 4 KB  z a-frags
    __shared__ __align__(16) short w1f[16 * 64 * 8];  // 16 KB W1 b-frags

#pragma unroll
    for (int p = 0; p < 2; ++p) {
      int u = p * 256 + tid;
      int row = u >> 5;                   // 0..15
      int c = (u & 31) * 4;               // 0..124
      float4v v = *(const float4v*)(z + (j0 + row) * EMB + c);
      int kt = c >> 5;
      int lane = ((c >> 3) & 3) * 16 + row;
      store_bf16x4(zf + (kt * 64 + lane) * 8 + (c & 7), v);
    }
    {
      const float* wbase = W1 + (hh * 64) * (2 * EMB) + which * EMB;
#pragma unroll
      for (int p = 0; p < 8; ++p) {
        int u = p * 256 + tid;
        int grow = u >> 5;                // 0..63
        int c = (u & 31) * 4;
        float4v v = *(const float4v*)(wbase + grow * (2 * EMB) + c);
        int kt = c >> 5;
        int ntl = grow >> 4;              // 0..3
        int lane = ((c >> 3) & 3) * 16 + (grow & 15);
        store_bf16x4(w1f + ((kt * 4 + ntl) * 64 + lane) * 8 + (c & 7), v);
      }
    }
    __syncthreads();

    int w = tid >> 6, l = tid & 63, r = l & 15, q = l >> 4;
    float4v acc = {};
#pragma unroll
    for (int kt = 0; kt < 4; ++kt) {
      short8 az = *(const short8*)(zf + (kt * 64 + l) * 8);
      short8 bf = *(const short8*)(w1f + ((kt * 4 + w) * 64 + l) * 8);
      acc = mfma16(az, bf, acc);
    }
    int gg = hh * 64 + w * 16 + r;
    float ba = which ? 0.0f : b1[gg];
    float* dstp = which ? Bbuf : Abuf;
#pragma unroll
    for (int reg = 0; reg < 4; ++reg)
      dstp[(j0 + q * 4 + reg) * HID + gg] = acc[reg] + ba;
  } else {
    // W2f swizzle: coalesced dwordx4 reads, scattered bf16 writes
    int s0 = (blk - 256) * 2048 + tid * 8;
    float4v v0 = *(const float4v*)(W2 + s0);
    float4v v1 = *(const float4v*)(W2 + s0 + 4);
    float vals[8] = {v0[0], v0[1], v0[2], v0[3], v1[0], v1[1], v1[2], v1[3]};
#pragma unroll
    for (int j = 0; j < 8; ++j) {
      int s = s0 + j;
      int g = s >> 7;
      int h = s & 127;
      int kt = h >> 5;
      int nt = g >> 4;
      int lane = ((h >> 3) & 3) * 16 + (g & 15);
      int dst = ((kt * 8 + nt) * 64 + lane) * 8 + (h & 7);
      unsigned u = __float_as_uint(vals[j]);
      W2f[dst] = (unsigned short)((u + 0x7FFFu + ((u >> 16) & 1u)) >> 16);  // RNE
    }
  }
}

// ---------------------------------------------------------------------------
// main: one block = 8i x 16j tile, 256 threads (4 waves), wave owns 2 i-rows.
// Swapped operands: D[g][pair] = W2 · h1^T.
// TWO-PASS g-split: pass 0 generates h1 (gelu once), stashes bf16 frags in
// regs (32 VGPR), accumulates g in [0,64) (acc = 32 regs); pass 1 replays the
// stash against W2's other half. Halving live acc frees ~30 regs, spent on an
// explicit next-kt prefetch of all 6 global float4 loads (the ~200-900 cy
// A-row gathers that previously stalled every kt).
// ---------------------------------------------------------------------------
__global__ __launch_bounds__(256, 4)
void fused_mlp_kernel(const float* __restrict__ Abuf, const float* __restrict__ Bbuf,
                      const float* __restrict__ W2f4,  // packed bf16 frags
                      const float* __restrict__ b2, const float* __restrict__ W3,
                      const float* __restrict__ b3, float* __restrict__ out) {
  __shared__ __align__(16) short s_w2[HID * HID];  // 32 KB, fragment order

  int tid = threadIdx.x;
  {
    const float4v* src = (const float4v*)W2f4;
    float4v* dst = (float4v*)s_w2;
#pragma unroll
    for (int t = 0; t < 8; ++t)
      dst[tid + t * 256] = src[tid + t * 256];
  }

  int w = tid >> 6, l = tid & 63, r = l & 15, q = l >> 4;
  int bi = (blockIdx.x >> 6) << 3;
  int bj = (blockIdx.x & 63) << 4;

  const float* Ap  = Abuf + (bj + r) * HID + q * 8;       // A'[j=bj+r]
  const float* Bp0 = Bbuf + (bi + 2 * w) * HID + q * 8;   // B[i0]
  const float* Bp1 = Bp0 + HID;                           // B[i1]

  short8 afs[4][2];                 // h1 frag stash: [kt][p], 32 VGPRs
  float4v s0 = {0.f, 0.f, 0.f, 0.f};
  float4v s1 = {0.f, 0.f, 0.f, 0.f};
  float4v acc[2][4];

  __syncthreads();

  // ---------------- pass 0: g in [0,64) ----------------
#pragma unroll
  for (int nt = 0; nt < 4; ++nt) {
    float4v bv = *(const float4v*)(b2 + nt * 16 + q * 4);
    acc[0][nt] = bv;
    acc[1][nt] = bv;
  }

  // preload kt=0 globals
  float4v a0  = *(const float4v*)(Ap);
  float4v a1  = *(const float4v*)(Ap + 4);
  float4v b00 = *(const float4v*)(Bp0);
  float4v b01 = *(const float4v*)(Bp0 + 4);
  float4v b10 = *(const float4v*)(Bp1);
  float4v b11 = *(const float4v*)(Bp1 + 4);

#pragma unroll
  for (int kt = 0; kt < 4; ++kt) {
    float4v ca0 = a0, ca1 = a1, cb00 = b00, cb01 = b01, cb10 = b10, cb11 = b11;
    if (kt < 3) {                       // issue next-kt loads before gelu chain
      int off = (kt + 1) * 32;
      a0  = *(const float4v*)(Ap + off);
      a1  = *(const float4v*)(Ap + off + 4);
      b00 = *(const float4v*)(Bp0 + off);
      b01 = *(const float4v*)(Bp0 + off + 4);
      b10 = *(const float4v*)(Bp1 + off);
      b11 = *(const float4v*)(Bp1 + off + 4);
    }
    short8 af0 = to_bf16x8(gelu4(ca0 + cb00), gelu4(ca1 + cb01));
    short8 af1 = to_bf16x8(gelu4(ca0 + cb10), gelu4(ca1 + cb11));
    afs[kt][0] = af0;
    afs[kt][1] = af1;

    const short8* wrow = (const short8*)s_w2 + kt * 512 + l;
#pragma unroll
    for (int nt = 0; nt < 4; ++nt) {
      short8 wf = wrow[nt * 64];        // stride-16B, conflict-free
      acc[0][nt] = mfma16(wf, af0, acc[0][nt]);
      acc[1][nt] = mfma16(wf, af1, acc[1][nt]);
    }
  }

#pragma unroll
  for (int nt = 0; nt < 4; ++nt) {
    float4v wv = *(const float4v*)(W3 + nt * 16 + q * 4);
    s0 = s0 + gelu4(acc[0][nt]) * wv;
    s1 = s1 + gelu4(acc[1][nt]) * wv;
  }

  // ---------------- pass 1: g in [64,128) — stash replay, no gelu/VMEM ----
#pragma unroll
  for (int nt = 0; nt < 4; ++nt) {
    float4v bv = *(const float4v*)(b2 + (nt + 4) * 16 + q * 4);
    acc[0][nt] = bv;
    acc[1][nt] = bv;
  }
#pragma unroll
  for (int kt = 0; kt < 4; ++kt) {
    short8 af0 = afs[kt][0];
    short8 af1 = afs[kt][1];
    const short8* wrow = (const short8*)s_w2 + kt * 512 + 4 * 64 + l;
#pragma unroll
    for (int nt = 0; nt < 4; ++nt) {
      short8 wf = wrow[nt * 64];
      acc[0][nt] = mfma16(wf, af0, acc[0][nt]);
      acc[1][nt] = mfma16(wf, af1, acc[1][nt]);
    }
  }
#pragma unroll
  for (int nt = 0; nt < 4; ++nt) {
    float4v wv = *(const float4v*)(W3 + (nt + 4) * 16 + q * 4);
    s0 = s0 + gelu4(acc[0][nt]) * wv;
    s1 = s1 + gelu4(acc[1][nt]) * wv;
  }

  // reduce + store
  float bias3 = b3[0];
  float sc0 = s0[0] + s0[1] + s0[2] + s0[3];
  float sc1 = s1[0] + s1[1] + s1[2] + s1[3];
  sc0 += __shfl_xor(sc0, 16, 64);
  sc0 += __shfl_xor(sc0, 32, 64);
  sc1 += __shfl_xor(sc1, 16, 64);
  sc1 += __shfl_xor(sc1, 32, 64);
  if (l < 16) {
    out[(bi + 2 * w) * NN + bj + l]     = sc0 + bias3;
    out[(bi + 2 * w + 1) * NN + bj + l] = sc1 + bias3;
  }
}

extern "C" void kernel_launch(void* const* d_in, const int* in_sizes, int n_in,
                              void* d_out, int out_size, void* d_ws, size_t ws_size,
                              hipStream_t stream) {
  const float* z1 = (const float*)d_in[0];
  const float* z2 = (const float*)d_in[1];
  const float* W1 = (const float*)d_in[2];
  const float* b1 = (const float*)d_in[3];
  const float* W2 = (const float*)d_in[4];
  const float* b2 = (const float*)d_in[5];
  const float* W3 = (const float*)d_in[6];
  const float* b3 = (const float*)d_in[7];
  float* out = (float*)d_out;

  float* Abuf = (float*)d_ws;                                // 512 KB
  float* Bbuf = Abuf + NN * HID;                             // 512 KB
  unsigned short* W2f = (unsigned short*)(Bbuf + NN * HID);  // 32 KB

  prep_kernel<<<264, 256, 0, stream>>>(z1, z2, W1, b1, W2, Abuf, Bbuf, W2f);
  fused_mlp_kernel<<<(NN / 8) * (NN / 16), 256, 0, stream>>>(
      Abuf, Bbuf, (const float*)W2f, b2, W3, b3, out);
}